// Round 1
// baseline (11725.381 us; speedup 1.0000x reference)
//
#include <hip/hip_runtime.h>
#include <math.h>

#define Bb   16
#define Tt   2048
#define Dd   1024
#define NL   4
#define MTOT (Bb * Tt)   // 32768

// ---------------------------------------------------------------------------
// tanh-approx GELU (JAX default: approximate=True)
// ---------------------------------------------------------------------------
__device__ __forceinline__ float gelu_tanh(float x) {
    float x3 = x * x * x;
    float u  = 0.7978845608028654f * (x + 0.044715f * x3);
    return 0.5f * x * (1.0f + tanhf(u));
}

// ---------------------------------------------------------------------------
// Generic fp32 GEMM: C[M,N] = A[M,K] @ B[K,N] (+ bias[n]) (+= C)
// 128x128 tile, BK=16, 256 threads, 8x8 per thread.
// All of M,N,K are multiples of the tile sizes in this problem.
// ---------------------------------------------------------------------------
template<int HAS_BIAS, int ACC>
__global__ __launch_bounds__(256)
void gemm128(const float* __restrict__ A, const float* __restrict__ Bm,
             const float* __restrict__ bias, float* __restrict__ C,
             int M, int N, int K)
{
    __shared__ __align__(16) float As[16][128];
    __shared__ __align__(16) float Bs[16][128];
    const int tid = threadIdx.x;
    const int n0  = blockIdx.x * 128;
    const int m0  = blockIdx.y * 128;
    const int tx  = tid & 15;
    const int ty  = tid >> 4;

    float acc[8][8];
#pragma unroll
    for (int i = 0; i < 8; ++i)
#pragma unroll
        for (int j = 0; j < 8; ++j) acc[i][j] = 0.0f;

    for (int k0 = 0; k0 < K; k0 += 16) {
#pragma unroll
        for (int l = 0; l < 2; ++l) {
            int idx = tid + l * 256;          // 0..511
            int row = idx >> 2;               // 0..127
            int c4  = (idx & 3) << 2;         // 0,4,8,12
            float4 v = *reinterpret_cast<const float4*>(
                &A[(size_t)(m0 + row) * K + k0 + c4]);
            As[c4 + 0][row] = v.x;
            As[c4 + 1][row] = v.y;
            As[c4 + 2][row] = v.z;
            As[c4 + 3][row] = v.w;
        }
#pragma unroll
        for (int l = 0; l < 2; ++l) {
            int idx = tid + l * 256;
            int kr  = idx >> 5;               // 0..15
            int c4  = (idx & 31) << 2;        // 0..124
            *reinterpret_cast<float4*>(&Bs[kr][c4]) =
                *reinterpret_cast<const float4*>(
                    &Bm[(size_t)(k0 + kr) * N + n0 + c4]);
        }
        __syncthreads();
#pragma unroll
        for (int kk = 0; kk < 16; ++kk) {
            float a[8], b[8];
            *reinterpret_cast<float4*>(&a[0]) =
                *reinterpret_cast<const float4*>(&As[kk][ty * 8]);
            *reinterpret_cast<float4*>(&a[4]) =
                *reinterpret_cast<const float4*>(&As[kk][ty * 8 + 4]);
            // split B columns: tx*4 and 64+tx*4 (2 lanes/bank -> conflict-free)
            *reinterpret_cast<float4*>(&b[0]) =
                *reinterpret_cast<const float4*>(&Bs[kk][tx * 4]);
            *reinterpret_cast<float4*>(&b[4]) =
                *reinterpret_cast<const float4*>(&Bs[kk][64 + tx * 4]);
#pragma unroll
            for (int i = 0; i < 8; ++i)
#pragma unroll
                for (int j = 0; j < 8; ++j)
                    acc[i][j] = fmaf(a[i], b[j], acc[i][j]);
        }
        __syncthreads();
    }

#pragma unroll
    for (int i = 0; i < 8; ++i) {
        int gr = m0 + ty * 8 + i;
#pragma unroll
        for (int j2 = 0; j2 < 2; ++j2) {
            int gc = n0 + j2 * 64 + tx * 4;
            size_t off = (size_t)gr * N + gc;
#pragma unroll
            for (int j = 0; j < 4; ++j) {
                float v = acc[i][j2 * 4 + j];
                if (HAS_BIAS) v += bias[gc + j];
                if (ACC)      v += C[off + j];
                C[off + j] = v;
            }
        }
    }
}

// ---------------------------------------------------------------------------
// Scan-doubling level: Sout[b,t,:] = Sin[b,t,:] + (t>=m ? Sin[b,t-m,:] @ P : 0)
// Same tiling as gemm128; rows with t<m load zeros for the A tile.
// ---------------------------------------------------------------------------
__global__ __launch_bounds__(256)
void scan_level(const float* __restrict__ Sin, const float* __restrict__ P,
                float* __restrict__ Sout, int m)
{
    __shared__ __align__(16) float As[16][128];
    __shared__ __align__(16) float Bs[16][128];
    const int tid = threadIdx.x;
    const int n0  = blockIdx.x * 128;
    const int m0  = blockIdx.y * 128;
    const int tx  = tid & 15;
    const int ty  = tid >> 4;

    float acc[8][8];
#pragma unroll
    for (int i = 0; i < 8; ++i)
#pragma unroll
        for (int j = 0; j < 8; ++j) acc[i][j] = 0.0f;

    for (int k0 = 0; k0 < Dd; k0 += 16) {
#pragma unroll
        for (int l = 0; l < 2; ++l) {
            int idx = tid + l * 256;
            int row = idx >> 2;
            int c4  = (idx & 3) << 2;
            int rg  = m0 + row;
            int t   = rg & (Tt - 1);
            float4 v = make_float4(0.0f, 0.0f, 0.0f, 0.0f);
            if (t >= m)
                v = *reinterpret_cast<const float4*>(
                    &Sin[(size_t)(rg - m) * Dd + k0 + c4]);
            As[c4 + 0][row] = v.x;
            As[c4 + 1][row] = v.y;
            As[c4 + 2][row] = v.z;
            As[c4 + 3][row] = v.w;
        }
#pragma unroll
        for (int l = 0; l < 2; ++l) {
            int idx = tid + l * 256;
            int kr  = idx >> 5;
            int c4  = (idx & 31) << 2;
            *reinterpret_cast<float4*>(&Bs[kr][c4]) =
                *reinterpret_cast<const float4*>(
                    &P[(size_t)(k0 + kr) * Dd + n0 + c4]);
        }
        __syncthreads();
#pragma unroll
        for (int kk = 0; kk < 16; ++kk) {
            float a[8], b[8];
            *reinterpret_cast<float4*>(&a[0]) =
                *reinterpret_cast<const float4*>(&As[kk][ty * 8]);
            *reinterpret_cast<float4*>(&a[4]) =
                *reinterpret_cast<const float4*>(&As[kk][ty * 8 + 4]);
            *reinterpret_cast<float4*>(&b[0]) =
                *reinterpret_cast<const float4*>(&Bs[kk][tx * 4]);
            *reinterpret_cast<float4*>(&b[4]) =
                *reinterpret_cast<const float4*>(&Bs[kk][64 + tx * 4]);
#pragma unroll
            for (int i = 0; i < 8; ++i)
#pragma unroll
                for (int j = 0; j < 8; ++j)
                    acc[i][j] = fmaf(a[i], b[j], acc[i][j]);
        }
        __syncthreads();
    }

#pragma unroll
    for (int i = 0; i < 8; ++i) {
        int gr = m0 + ty * 8 + i;
#pragma unroll
        for (int j2 = 0; j2 < 2; ++j2) {
            int gc = n0 + j2 * 64 + tx * 4;
            size_t off = (size_t)gr * Dd + gc;
#pragma unroll
            for (int j = 0; j < 4; ++j)
                Sout[off + j] = Sin[off + j] + acc[i][j2 * 4 + j];
        }
    }
}

// ---------------------------------------------------------------------------
// Sequential carry step i (i=1..31):
//   for all b, t in [64i, 64i+64): S[b,t,:] += S[b,t-64,:] @ P64
// grid = (16 n-tiles, 16 batches); 64x64 tile, BK=16, 4x4 per thread.
// ---------------------------------------------------------------------------
__global__ __launch_bounds__(256)
void seq_step(float* __restrict__ S, const float* __restrict__ P, int step)
{
    __shared__ __align__(16) float As[16][64];
    __shared__ __align__(16) float Bs[16][64];
    const int tid  = threadIdx.x;
    const int n0   = blockIdx.x * 64;
    const int b    = blockIdx.y;
    const int src0 = b * Tt + (step - 1) * 64;
    const int dst0 = b * Tt + step * 64;
    const int tx   = tid & 15;
    const int ty   = tid >> 4;

    float acc[4][4];
#pragma unroll
    for (int i = 0; i < 4; ++i)
#pragma unroll
        for (int j = 0; j < 4; ++j) acc[i][j] = 0.0f;

    for (int k0 = 0; k0 < Dd; k0 += 16) {
        {
            int row = tid >> 2;               // 0..63
            int c4  = (tid & 3) << 2;
            float4 v = *reinterpret_cast<const float4*>(
                &S[(size_t)(src0 + row) * Dd + k0 + c4]);
            As[c4 + 0][row] = v.x;
            As[c4 + 1][row] = v.y;
            As[c4 + 2][row] = v.z;
            As[c4 + 3][row] = v.w;
        }
        {
            int kr = tid >> 4;                // 0..15
            int c4 = (tid & 15) << 2;         // 0..60
            *reinterpret_cast<float4*>(&Bs[kr][c4]) =
                *reinterpret_cast<const float4*>(
                    &P[(size_t)(k0 + kr) * Dd + n0 + c4]);
        }
        __syncthreads();
#pragma unroll
        for (int kk = 0; kk < 16; ++kk) {
            float a[4], bv[4];
            *reinterpret_cast<float4*>(&a[0]) =
                *reinterpret_cast<const float4*>(&As[kk][ty * 4]);
            *reinterpret_cast<float4*>(&bv[0]) =
                *reinterpret_cast<const float4*>(&Bs[kk][tx * 4]);
#pragma unroll
            for (int i = 0; i < 4; ++i)
#pragma unroll
                for (int j = 0; j < 4; ++j)
                    acc[i][j] = fmaf(a[i], bv[j], acc[i][j]);
        }
        __syncthreads();
    }

#pragma unroll
    for (int i = 0; i < 4; ++i) {
        size_t off = (size_t)(dst0 + ty * 4 + i) * Dd + n0 + tx * 4;
#pragma unroll
        for (int j = 0; j < 4; ++j)
            S[off + j] += acc[i][j];
    }
}

// ---------------------------------------------------------------------------
// BatchNorm partial reduction: 256 blocks x 128 rows each.
// partial_sum[blk][d], partial_sq[blk][d]
// ---------------------------------------------------------------------------
__global__ __launch_bounds__(256)
void bn_partial(const float* __restrict__ Z,
                float* __restrict__ ps, float* __restrict__ pq)
{
    const int tid = threadIdx.x;
    const int blk = blockIdx.x;
    const size_t base = (size_t)blk * 128 * Dd;
    float s0 = 0.f, s1 = 0.f, s2 = 0.f, s3 = 0.f;
    float q0 = 0.f, q1 = 0.f, q2 = 0.f, q3 = 0.f;
    for (int r = 0; r < 128; ++r) {
        const float* zr = Z + base + (size_t)r * Dd;
        float v0 = zr[tid];       s0 += v0; q0 += v0 * v0;
        float v1 = zr[tid + 256]; s1 += v1; q1 += v1 * v1;
        float v2 = zr[tid + 512]; s2 += v2; q2 += v2 * v2;
        float v3 = zr[tid + 768]; s3 += v3; q3 += v3 * v3;
    }
    ps[blk * Dd + tid]       = s0;
    ps[blk * Dd + tid + 256] = s1;
    ps[blk * Dd + tid + 512] = s2;
    ps[blk * Dd + tid + 768] = s3;
    pq[blk * Dd + tid]       = q0;
    pq[blk * Dd + tid + 256] = q1;
    pq[blk * Dd + tid + 512] = q2;
    pq[blk * Dd + tid + 768] = q3;
}

// ---------------------------------------------------------------------------
// Finalize BN stats per channel -> affine a[d], c[d]:  zn*scale+bias = z*a + c
// ---------------------------------------------------------------------------
__global__ __launch_bounds__(256)
void bn_stats(const float* __restrict__ ps, const float* __restrict__ pq,
              const float* __restrict__ scale, const float* __restrict__ bias,
              float* __restrict__ Av, float* __restrict__ Cv)
{
    const int d = blockIdx.x * 256 + threadIdx.x;
    float s = 0.f, q = 0.f;
    for (int p = 0; p < 256; ++p) {
        s += ps[p * Dd + d];
        q += pq[p * Dd + d];
    }
    const float invN = 1.0f / 32768.0f;
    float mean = s * invN;
    float var  = q * invN - mean * mean;
    float rs   = rsqrtf(var + 1e-5f);
    float a    = rs * scale[d];
    Av[d] = a;
    Cv[d] = bias[d] - mean * a;
}

// ---------------------------------------------------------------------------
// y_out = gelu(z*a[d] + c[d]) + y_in   (elementwise, float4-vectorized)
// ---------------------------------------------------------------------------
__global__ __launch_bounds__(256)
void residual_gelu(const float* __restrict__ Z, const float* __restrict__ Yin,
                   float* __restrict__ Yout,
                   const float* __restrict__ Av, const float* __restrict__ Cv)
{
    const float4* z4 = reinterpret_cast<const float4*>(Z);
    const float4* y4 = reinterpret_cast<const float4*>(Yin);
    float4*       o4 = reinterpret_cast<float4*>(Yout);
    const float4* a4 = reinterpret_cast<const float4*>(Av);
    const float4* c4 = reinterpret_cast<const float4*>(Cv);
    const int n4 = MTOT * Dd / 4;
    for (int i = blockIdx.x * blockDim.x + threadIdx.x; i < n4;
         i += gridDim.x * blockDim.x) {
        int d4 = i & (Dd / 4 - 1);
        float4 z = z4[i], y = y4[i], a = a4[d4], c = c4[d4];
        float4 o;
        o.x = gelu_tanh(fmaf(z.x, a.x, c.x)) + y.x;
        o.y = gelu_tanh(fmaf(z.y, a.y, c.y)) + y.y;
        o.z = gelu_tanh(fmaf(z.z, a.z, c.z)) + y.z;
        o.w = gelu_tanh(fmaf(z.w, a.w, c.w)) + y.w;
        o4[i] = o;
    }
}

// ---------------------------------------------------------------------------
extern "C" void kernel_launch(void* const* d_in, const int* in_sizes, int n_in,
                              void* d_out, int out_size, void* d_ws, size_t ws_size,
                              hipStream_t stream)
{
    const float* x    = (const float*)d_in[0];
    const float* Wi   = (const float*)d_in[1];
    const float* bi   = (const float*)d_in[2];
    const float* Wh   = (const float*)d_in[3];
    const float* mlpW = (const float*)d_in[4];
    const float* mlpb = (const float*)d_in[5];
    const float* bns  = (const float*)d_in[6];
    const float* bnb  = (const float*)d_in[7];
    float* out = (float*)d_out;

    float* ws   = (float*)d_ws;
    float* S0   = ws;                                  // 33,554,432 floats
    float* Pa   = S0 + (size_t)MTOT * Dd;              // 1,048,576
    float* Pb   = Pa + (size_t)Dd * Dd;                // 1,048,576
    float* psum = Pb + (size_t)Dd * Dd;                // 262,144
    float* psq  = psum + 256 * Dd;                     // 262,144
    float* abuf = psq + 256 * Dd;                      // 1024
    float* cbuf = abuf + Dd;                           // 1024

    const dim3 gBig(Dd / 128, MTOT / 128);   // (8, 256)
    const dim3 gSq (Dd / 128, Dd / 128);     // (8, 8)
    const dim3 gSeq(Dd / 64, Bb);            // (16, 16)

    // Phase 1: xp = x @ Wi + bi  -> S0
    gemm128<1, 0><<<gBig, 256, 0, stream>>>(x, Wi, bi, S0, MTOT, Dd, Dd);

    // Phase 2: scan doubling, ping-pong S0 <-> out; squarings interleaved.
    scan_level<<<gBig, 256, 0, stream>>>(S0, Wh, out, 1);
    gemm128<0, 0><<<gSq, 256, 0, stream>>>(Wh, Wh, nullptr, Pa, Dd, Dd, Dd);  // P2
    scan_level<<<gBig, 256, 0, stream>>>(out, Pa, S0, 2);
    gemm128<0, 0><<<gSq, 256, 0, stream>>>(Pa, Pa, nullptr, Pb, Dd, Dd, Dd);  // P4
    scan_level<<<gBig, 256, 0, stream>>>(S0, Pb, out, 4);
    gemm128<0, 0><<<gSq, 256, 0, stream>>>(Pb, Pb, nullptr, Pa, Dd, Dd, Dd);  // P8
    scan_level<<<gBig, 256, 0, stream>>>(out, Pa, S0, 8);
    gemm128<0, 0><<<gSq, 256, 0, stream>>>(Pa, Pa, nullptr, Pb, Dd, Dd, Dd);  // P16
    scan_level<<<gBig, 256, 0, stream>>>(S0, Pb, out, 16);
    gemm128<0, 0><<<gSq, 256, 0, stream>>>(Pb, Pb, nullptr, Pa, Dd, Dd, Dd);  // P32
    scan_level<<<gBig, 256, 0, stream>>>(out, Pa, S0, 32);
    gemm128<0, 0><<<gSq, 256, 0, stream>>>(Pa, Pa, nullptr, Pb, Dd, Dd, Dd);  // P64

    // Phase 3: 31 sequential carry steps with P64 (in Pb)
    for (int i = 1; i < 32; ++i)
        seq_step<<<gSeq, 256, 0, stream>>>(S0, Pb, i);

    // Phase 4: residual MLP stack; z lives in d_out, y lives in S0
    for (int l = 0; l < NL; ++l) {
        gemm128<1, 0><<<gBig, 256, 0, stream>>>(
            S0, mlpW + (size_t)l * Dd * Dd, mlpb + (size_t)l * Dd, out,
            MTOT, Dd, Dd);
        bn_partial<<<256, 256, 0, stream>>>(out, psum, psq);
        bn_stats<<<4, 256, 0, stream>>>(psum, psq, bns + (size_t)l * Dd,
                                        bnb + (size_t)l * Dd, abuf, cbuf);
        residual_gelu<<<1024, 256, 0, stream>>>(
            out, S0, (l < NL - 1) ? S0 : out, abuf, cbuf);
    }
}

// Round 2
// 5534.364 us; speedup vs baseline: 2.1186x; 2.1186x over previous
//
#include <hip/hip_runtime.h>
#include <math.h>

#define Bb   16
#define Tt   2048
#define Dd   1024
#define NL   4
#define MTOT (Bb * Tt)   // 32768

typedef float f32x4 __attribute__((ext_vector_type(4)));
typedef short bf16x8 __attribute__((ext_vector_type(8)));

// ---------------------------------------------------------------------------
// bf16 helpers (RNE)
// ---------------------------------------------------------------------------
__device__ __forceinline__ unsigned short f2bf_rne(float x) {
    unsigned u = __float_as_uint(x);
    u += 0x7fffu + ((u >> 16) & 1u);
    return (unsigned short)(u >> 16);
}
__device__ __forceinline__ float bf2f(unsigned short h) {
    return __uint_as_float(((unsigned)h) << 16);
}

// ---------------------------------------------------------------------------
// tanh-approx GELU (JAX default: approximate=True)
// ---------------------------------------------------------------------------
__device__ __forceinline__ float gelu_tanh(float x) {
    float x3 = x * x * x;
    float u  = 0.7978845608028654f * (x + 0.044715f * x3);
    return 0.5f * x * (1.0f + tanhf(u));
}

// ---------------------------------------------------------------------------
// Split + transpose a [1024,1024] fp32 matrix into bf16 hi/lo, output [n][k].
// grid (32,32), 256 threads.
// ---------------------------------------------------------------------------
__global__ __launch_bounds__(256)
void split_bt(const float* __restrict__ B, short* __restrict__ ht,
              short* __restrict__ lt)
{
    __shared__ float tile[32][33];
    const int t  = threadIdx.x;
    const int r  = t >> 3;          // 0..31
    const int c  = (t & 7) * 4;     // 0,4,...,28
    const int kb = blockIdx.y * 32;
    const int nb = blockIdx.x * 32;
    float4 v = *reinterpret_cast<const float4*>(
        &B[(size_t)(kb + r) * Dd + nb + c]);
    tile[r][c + 0] = v.x; tile[r][c + 1] = v.y;
    tile[r][c + 2] = v.z; tile[r][c + 3] = v.w;
    __syncthreads();
    unsigned h[4], lo[4];
#pragma unroll
    for (int q = 0; q < 4; ++q) {
        float f = tile[c + q][r];           // B[kb+c+q][nb+r]
        unsigned short hh = f2bf_rne(f);
        float rem = f - bf2f(hh);
        h[q]  = hh;
        lo[q] = f2bf_rne(rem);
    }
    uint2 hw, lw;
    hw.x = h[0]  | (h[1]  << 16); hw.y = h[2]  | (h[3]  << 16);
    lw.x = lo[0] | (lo[1] << 16); lw.y = lo[2] | (lo[3] << 16);
    size_t off = (size_t)(nb + r) * Dd + kb + c;
    *reinterpret_cast<uint2*>(&ht[off]) = hw;
    *reinterpret_cast<uint2*>(&lt[off]) = lw;
}

// ---------------------------------------------------------------------------
// Split-precision MFMA GEMM (effective fp32 via 3 bf16 MFMAs).
// SCAN=0: Cout[r,c] = sum_k A[r,k]*B[k,c] + bias[c]
// SCAN=1: Cout[r,c] = Sin[r,c] + sum_k A'[r,k]*B[k,c],
//         A'[r] = (t>=m) ? A[r-m] : 0,  t = r mod Tt
// B given pre-split/transposed: Bth/Btl are [n][k] bf16.
// 128x128 tile, BK=32, 256 threads = 4 waves (2x2 of 64x64 each).
// ---------------------------------------------------------------------------
template<int SCAN>
__global__ __launch_bounds__(256, 2)
void mfma_gemm(const float* __restrict__ A,
               const short* __restrict__ Bth, const short* __restrict__ Btl,
               const float* __restrict__ bias,
               const float* __restrict__ Sin,
               float* __restrict__ Cout, int m)
{
    // 4 planes, rows padded to 40 shorts (80B): Ah, Al, Bh, Bl
    __shared__ __align__(16) short lds[4 * 5120];
    const int tid  = threadIdx.x;
    const int lane = tid & 63;
    const int w    = tid >> 6;
    const int n0   = blockIdx.x * 128;
    const int m0   = blockIdx.y * 128;
    const int wm0  = (w >> 1) * 64;
    const int wn0  = (w & 1) * 64;

    // A staging map: round p: row = p*32 + (tid>>3), col = (tid&7)*4
    const int ar = tid >> 3;
    const int ac = (tid & 7) * 4;
    // B staging map: round q: nrow = q*64 + (tid>>2), slot = tid&3 (8 shorts)
    const int bnr = tid >> 2;
    const int bsg = tid & 3;

    int  arow_src[4];
    bool avalid[4];
#pragma unroll
    for (int p = 0; p < 4; ++p) {
        int rg = m0 + p * 32 + ar;
        int t  = rg & (Tt - 1);
        bool v = (t >= m);
        avalid[p]   = v;
        arow_src[p] = v ? (rg - m) : rg;
    }

    f32x4 acc[4][4];
#pragma unroll
    for (int i = 0; i < 4; ++i)
#pragma unroll
        for (int j = 0; j < 4; ++j) acc[i][j] = (f32x4){0.f, 0.f, 0.f, 0.f};

    // loop-invariant LDS fragment offsets (short units)
    int a_off[4], b_off[4];
#pragma unroll
    for (int i = 0; i < 4; ++i) {
        int r = wm0 + i * 16 + (lane & 15);
        a_off[i] = r * 40 + (lane >> 4) * 8;
        int n = wn0 + i * 16 + (lane & 15);
        b_off[i] = 2 * 5120 + n * 40 + (lane >> 4) * 8;
    }

    for (int k0 = 0; k0 < Dd; k0 += 32) {
        __syncthreads();   // reads of previous tile complete before overwrite
        // ---- stage A: fp32 -> (hi, lo) bf16 ----
#pragma unroll
        for (int p = 0; p < 4; ++p) {
            float4 v = *reinterpret_cast<const float4*>(
                &A[(size_t)arow_src[p] * Dd + k0 + ac]);
            if (SCAN && !avalid[p]) v = make_float4(0.f, 0.f, 0.f, 0.f);
            int row = p * 32 + ar;
            int wo  = row * 40 + ((ac >> 3) << 3) + (ac & 7);
            unsigned short h0 = f2bf_rne(v.x), h1 = f2bf_rne(v.y),
                           h2 = f2bf_rne(v.z), h3 = f2bf_rne(v.w);
            unsigned short g0 = f2bf_rne(v.x - bf2f(h0)),
                           g1 = f2bf_rne(v.y - bf2f(h1)),
                           g2 = f2bf_rne(v.z - bf2f(h2)),
                           g3 = f2bf_rne(v.w - bf2f(h3));
            uint2 hw, lw;
            hw.x = (unsigned)h0 | ((unsigned)h1 << 16);
            hw.y = (unsigned)h2 | ((unsigned)h3 << 16);
            lw.x = (unsigned)g0 | ((unsigned)g1 << 16);
            lw.y = (unsigned)g2 | ((unsigned)g3 << 16);
            *reinterpret_cast<uint2*>(&lds[wo])        = hw;
            *reinterpret_cast<uint2*>(&lds[wo + 5120]) = lw;
        }
        // ---- stage B: copy pre-split bf16 ----
#pragma unroll
        for (int q = 0; q < 2; ++q) {
            int n = q * 64 + bnr;
            size_t g = (size_t)(n0 + n) * Dd + k0 + bsg * 8;
            int wo = 2 * 5120 + n * 40 + bsg * 8;
            *reinterpret_cast<int4*>(&lds[wo]) =
                *reinterpret_cast<const int4*>(&Bth[g]);
            *reinterpret_cast<int4*>(&lds[wo + 5120]) =
                *reinterpret_cast<const int4*>(&Btl[g]);
        }
        __syncthreads();
        // ---- compute ----
        bf16x8 ah[4], al[4], bh[4], bl[4];
#pragma unroll
        for (int i = 0; i < 4; ++i) {
            ah[i] = *reinterpret_cast<const bf16x8*>(&lds[a_off[i]]);
            al[i] = *reinterpret_cast<const bf16x8*>(&lds[a_off[i] + 5120]);
            bh[i] = *reinterpret_cast<const bf16x8*>(&lds[b_off[i]]);
            bl[i] = *reinterpret_cast<const bf16x8*>(&lds[b_off[i] + 5120]);
        }
#pragma unroll
        for (int i = 0; i < 4; ++i)
#pragma unroll
            for (int j = 0; j < 4; ++j) {
                acc[i][j] = __builtin_amdgcn_mfma_f32_16x16x32_bf16(
                    ah[i], bh[j], acc[i][j], 0, 0, 0);
                acc[i][j] = __builtin_amdgcn_mfma_f32_16x16x32_bf16(
                    ah[i], bl[j], acc[i][j], 0, 0, 0);
                acc[i][j] = __builtin_amdgcn_mfma_f32_16x16x32_bf16(
                    al[i], bh[j], acc[i][j], 0, 0, 0);
            }
    }

    // ---- epilogue ----
#pragma unroll
    for (int j = 0; j < 4; ++j) {
        int col = n0 + wn0 + j * 16 + (lane & 15);
        float bj = SCAN ? 0.f : bias[col];
#pragma unroll
        for (int i = 0; i < 4; ++i) {
            int rbase = m0 + wm0 + i * 16 + (lane >> 4) * 4;
#pragma unroll
            for (int e = 0; e < 4; ++e) {
                size_t off = (size_t)(rbase + e) * Dd + col;
                float v = acc[i][j][e];
                if (SCAN) v += Sin[off];
                else      v += bj;
                Cout[off] = v;
            }
        }
    }
}

// ---------------------------------------------------------------------------
// fp32 GEMM for the small 1024^3 power squarings (kept from round 1)
// ---------------------------------------------------------------------------
template<int HAS_BIAS, int ACC>
__global__ __launch_bounds__(256)
void gemm128(const float* __restrict__ A, const float* __restrict__ Bm,
             const float* __restrict__ bias, float* __restrict__ C,
             int M, int N, int K)
{
    __shared__ __align__(16) float As[16][128];
    __shared__ __align__(16) float Bs[16][128];
    const int tid = threadIdx.x;
    const int n0  = blockIdx.x * 128;
    const int m0  = blockIdx.y * 128;
    const int tx  = tid & 15;
    const int ty  = tid >> 4;

    float acc[8][8];
#pragma unroll
    for (int i = 0; i < 8; ++i)
#pragma unroll
        for (int j = 0; j < 8; ++j) acc[i][j] = 0.0f;

    for (int k0 = 0; k0 < K; k0 += 16) {
#pragma unroll
        for (int l = 0; l < 2; ++l) {
            int idx = tid + l * 256;
            int row = idx >> 2;
            int c4  = (idx & 3) << 2;
            float4 v = *reinterpret_cast<const float4*>(
                &A[(size_t)(m0 + row) * K + k0 + c4]);
            As[c4 + 0][row] = v.x;
            As[c4 + 1][row] = v.y;
            As[c4 + 2][row] = v.z;
            As[c4 + 3][row] = v.w;
        }
#pragma unroll
        for (int l = 0; l < 2; ++l) {
            int idx = tid + l * 256;
            int kr  = idx >> 5;
            int c4  = (idx & 31) << 2;
            *reinterpret_cast<float4*>(&Bs[kr][c4]) =
                *reinterpret_cast<const float4*>(
                    &Bm[(size_t)(k0 + kr) * N + n0 + c4]);
        }
        __syncthreads();
#pragma unroll
        for (int kk = 0; kk < 16; ++kk) {
            float a[8], b[8];
            *reinterpret_cast<float4*>(&a[0]) =
                *reinterpret_cast<const float4*>(&As[kk][ty * 8]);
            *reinterpret_cast<float4*>(&a[4]) =
                *reinterpret_cast<const float4*>(&As[kk][ty * 8 + 4]);
            *reinterpret_cast<float4*>(&b[0]) =
                *reinterpret_cast<const float4*>(&Bs[kk][tx * 4]);
            *reinterpret_cast<float4*>(&b[4]) =
                *reinterpret_cast<const float4*>(&Bs[kk][64 + tx * 4]);
#pragma unroll
            for (int i = 0; i < 8; ++i)
#pragma unroll
                for (int j = 0; j < 8; ++j)
                    acc[i][j] = fmaf(a[i], b[j], acc[i][j]);
        }
        __syncthreads();
    }

#pragma unroll
    for (int i = 0; i < 8; ++i) {
        int gr = m0 + ty * 8 + i;
#pragma unroll
        for (int j2 = 0; j2 < 2; ++j2) {
            int gc = n0 + j2 * 64 + tx * 4;
            size_t off = (size_t)gr * N + gc;
#pragma unroll
            for (int j = 0; j < 4; ++j) {
                float v = acc[i][j2 * 4 + j];
                if (HAS_BIAS) v += bias[gc + j];
                if (ACC)      v += C[off + j];
                C[off + j] = v;
            }
        }
    }
}

// ---------------------------------------------------------------------------
// Sequential carry step i (i=1..31):
//   for all b, t in [64i, 64i+64): S[b,t,:] += S[b,t-64,:] @ P64
// ---------------------------------------------------------------------------
__global__ __launch_bounds__(256)
void seq_step(float* __restrict__ S, const float* __restrict__ P, int step)
{
    __shared__ __align__(16) float As[16][64];
    __shared__ __align__(16) float Bs[16][64];
    const int tid  = threadIdx.x;
    const int n0   = blockIdx.x * 64;
    const int b    = blockIdx.y;
    const int src0 = b * Tt + (step - 1) * 64;
    const int dst0 = b * Tt + step * 64;
    const int tx   = tid & 15;
    const int ty   = tid >> 4;

    float acc[4][4];
#pragma unroll
    for (int i = 0; i < 4; ++i)
#pragma unroll
        for (int j = 0; j < 4; ++j) acc[i][j] = 0.0f;

    for (int k0 = 0; k0 < Dd; k0 += 16) {
        {
            int row = tid >> 2;
            int c4  = (tid & 3) << 2;
            float4 v = *reinterpret_cast<const float4*>(
                &S[(size_t)(src0 + row) * Dd + k0 + c4]);
            As[c4 + 0][row] = v.x;
            As[c4 + 1][row] = v.y;
            As[c4 + 2][row] = v.z;
            As[c4 + 3][row] = v.w;
        }
        {
            int kr = tid >> 4;
            int c4 = (tid & 15) << 2;
            *reinterpret_cast<float4*>(&Bs[kr][c4]) =
                *reinterpret_cast<const float4*>(
                    &P[(size_t)(k0 + kr) * Dd + n0 + c4]);
        }
        __syncthreads();
#pragma unroll
        for (int kk = 0; kk < 16; ++kk) {
            float a[4], bv[4];
            *reinterpret_cast<float4*>(&a[0]) =
                *reinterpret_cast<const float4*>(&As[kk][ty * 4]);
            *reinterpret_cast<float4*>(&bv[0]) =
                *reinterpret_cast<const float4*>(&Bs[kk][tx * 4]);
#pragma unroll
            for (int i = 0; i < 4; ++i)
#pragma unroll
                for (int j = 0; j < 4; ++j)
                    acc[i][j] = fmaf(a[i], bv[j], acc[i][j]);
        }
        __syncthreads();
    }

#pragma unroll
    for (int i = 0; i < 4; ++i) {
        size_t off = (size_t)(dst0 + ty * 4 + i) * Dd + n0 + tx * 4;
#pragma unroll
        for (int j = 0; j < 4; ++j)
            S[off + j] += acc[i][j];
    }
}

// ---------------------------------------------------------------------------
// BatchNorm partial reduction: 256 blocks x 128 rows each.
// ---------------------------------------------------------------------------
__global__ __launch_bounds__(256)
void bn_partial(const float* __restrict__ Z,
                float* __restrict__ ps, float* __restrict__ pq)
{
    const int tid = threadIdx.x;
    const int blk = blockIdx.x;
    const size_t base = (size_t)blk * 128 * Dd;
    float s0 = 0.f, s1 = 0.f, s2 = 0.f, s3 = 0.f;
    float q0 = 0.f, q1 = 0.f, q2 = 0.f, q3 = 0.f;
    for (int r = 0; r < 128; ++r) {
        const float* zr = Z + base + (size_t)r * Dd;
        float v0 = zr[tid];       s0 += v0; q0 += v0 * v0;
        float v1 = zr[tid + 256]; s1 += v1; q1 += v1 * v1;
        float v2 = zr[tid + 512]; s2 += v2; q2 += v2 * v2;
        float v3 = zr[tid + 768]; s3 += v3; q3 += v3 * v3;
    }
    ps[blk * Dd + tid]       = s0;
    ps[blk * Dd + tid + 256] = s1;
    ps[blk * Dd + tid + 512] = s2;
    ps[blk * Dd + tid + 768] = s3;
    pq[blk * Dd + tid]       = q0;
    pq[blk * Dd + tid + 256] = q1;
    pq[blk * Dd + tid + 512] = q2;
    pq[blk * Dd + tid + 768] = q3;
}

// ---------------------------------------------------------------------------
__global__ __launch_bounds__(256)
void bn_stats(const float* __restrict__ ps, const float* __restrict__ pq,
              const float* __restrict__ scale, const float* __restrict__ bias,
              float* __restrict__ Av, float* __restrict__ Cv)
{
    const int d = blockIdx.x * 256 + threadIdx.x;
    float s = 0.f, q = 0.f;
    for (int p = 0; p < 256; ++p) {
        s += ps[p * Dd + d];
        q += pq[p * Dd + d];
    }
    const float invN = 1.0f / 32768.0f;
    float mean = s * invN;
    float var  = q * invN - mean * mean;
    float rs   = rsqrtf(var + 1e-5f);
    float a    = rs * scale[d];
    Av[d] = a;
    Cv[d] = bias[d] - mean * a;
}

// ---------------------------------------------------------------------------
__global__ __launch_bounds__(256)
void residual_gelu(const float* __restrict__ Z, const float* __restrict__ Yin,
                   float* __restrict__ Yout,
                   const float* __restrict__ Av, const float* __restrict__ Cv)
{
    const float4* z4 = reinterpret_cast<const float4*>(Z);
    const float4* y4 = reinterpret_cast<const float4*>(Yin);
    float4*       o4 = reinterpret_cast<float4*>(Yout);
    const float4* a4 = reinterpret_cast<const float4*>(Av);
    const float4* c4 = reinterpret_cast<const float4*>(Cv);
    const int n4 = MTOT * Dd / 4;
    for (int i = blockIdx.x * blockDim.x + threadIdx.x; i < n4;
         i += gridDim.x * blockDim.x) {
        int d4 = i & (Dd / 4 - 1);
        float4 z = z4[i], y = y4[i], a = a4[d4], c = c4[d4];
        float4 o;
        o.x = gelu_tanh(fmaf(z.x, a.x, c.x)) + y.x;
        o.y = gelu_tanh(fmaf(z.y, a.y, c.y)) + y.y;
        o.z = gelu_tanh(fmaf(z.z, a.z, c.z)) + y.z;
        o.w = gelu_tanh(fmaf(z.w, a.w, c.w)) + y.w;
        o4[i] = o;
    }
}

// ---------------------------------------------------------------------------
extern "C" void kernel_launch(void* const* d_in, const int* in_sizes, int n_in,
                              void* d_out, int out_size, void* d_ws, size_t ws_size,
                              hipStream_t stream)
{
    const float* x    = (const float*)d_in[0];
    const float* Wi   = (const float*)d_in[1];
    const float* bi   = (const float*)d_in[2];
    const float* Wh   = (const float*)d_in[3];
    const float* mlpW = (const float*)d_in[4];
    const float* mlpb = (const float*)d_in[5];
    const float* bns  = (const float*)d_in[6];
    const float* bnb  = (const float*)d_in[7];
    float* out = (float*)d_out;

    float* ws   = (float*)d_ws;
    float* S0   = ws;                                  // 33,554,432 floats
    float* Pa   = S0 + (size_t)MTOT * Dd;              // 1,048,576
    float* Pb   = Pa + (size_t)Dd * Dd;                // 1,048,576
    float* psum = Pb + (size_t)Dd * Dd;                // 262,144
    float* psq  = psum + 256 * Dd;                     // 262,144
    float* abuf = psq + 256 * Dd;                      // 1024
    float* cbuf = abuf + Dd;                           // 1024
    short* Bth  = (short*)(cbuf + Dd);                 // 1,048,576 shorts
    short* Btl  = Bth + (size_t)Dd * Dd;               // 1,048,576 shorts

    const dim3 gBig(Dd / 128, MTOT / 128);   // (8, 256)
    const dim3 gSq (Dd / 128, Dd / 128);     // (8, 8)
    const dim3 gSeq(Dd / 64, Bb);            // (16, 16)
    const dim3 gBt (32, 32);

    // Phase 1: xp = x @ Wi + bi  -> S0   (split-MFMA)
    split_bt<<<gBt, 256, 0, stream>>>(Wi, Bth, Btl);
    mfma_gemm<0><<<gBig, 256, 0, stream>>>(x, Bth, Btl, bi, nullptr, S0, 0);

    // Phase 2: scan doubling (split-MFMA), ping-pong S0 <-> out.
    split_bt<<<gBt, 256, 0, stream>>>(Wh, Bth, Btl);
    mfma_gemm<1><<<gBig, 256, 0, stream>>>(S0, Bth, Btl, nullptr, S0, out, 1);
    gemm128<0, 0><<<gSq, 256, 0, stream>>>(Wh, Wh, nullptr, Pa, Dd, Dd, Dd);  // P2
    split_bt<<<gBt, 256, 0, stream>>>(Pa, Bth, Btl);
    mfma_gemm<1><<<gBig, 256, 0, stream>>>(out, Bth, Btl, nullptr, out, S0, 2);
    gemm128<0, 0><<<gSq, 256, 0, stream>>>(Pa, Pa, nullptr, Pb, Dd, Dd, Dd);  // P4
    split_bt<<<gBt, 256, 0, stream>>>(Pb, Bth, Btl);
    mfma_gemm<1><<<gBig, 256, 0, stream>>>(S0, Bth, Btl, nullptr, S0, out, 4);
    gemm128<0, 0><<<gSq, 256, 0, stream>>>(Pb, Pb, nullptr, Pa, Dd, Dd, Dd);  // P8
    split_bt<<<gBt, 256, 0, stream>>>(Pa, Bth, Btl);
    mfma_gemm<1><<<gBig, 256, 0, stream>>>(out, Bth, Btl, nullptr, out, S0, 8);
    gemm128<0, 0><<<gSq, 256, 0, stream>>>(Pa, Pa, nullptr, Pb, Dd, Dd, Dd);  // P16
    split_bt<<<gBt, 256, 0, stream>>>(Pb, Bth, Btl);
    mfma_gemm<1><<<gBig, 256, 0, stream>>>(S0, Bth, Btl, nullptr, S0, out, 16);
    gemm128<0, 0><<<gSq, 256, 0, stream>>>(Pb, Pb, nullptr, Pa, Dd, Dd, Dd);  // P32
    split_bt<<<gBt, 256, 0, stream>>>(Pa, Bth, Btl);
    mfma_gemm<1><<<gBig, 256, 0, stream>>>(out, Bth, Btl, nullptr, out, S0, 32);
    gemm128<0, 0><<<gSq, 256, 0, stream>>>(Pa, Pa, nullptr, Pb, Dd, Dd, Dd);  // P64

    // Phase 3: 31 sequential carry steps with P64 (fp32, in Pb)
    for (int i = 1; i < 32; ++i)
        seq_step<<<gSeq, 256, 0, stream>>>(S0, Pb, i);

    // Phase 4: residual MLP stack (split-MFMA GEMMs); y in S0, z in d_out
    for (int l = 0; l < NL; ++l) {
        split_bt<<<gBt, 256, 0, stream>>>(mlpW + (size_t)l * Dd * Dd, Bth, Btl);
        mfma_gemm<0><<<gBig, 256, 0, stream>>>(
            S0, Bth, Btl, mlpb + (size_t)l * Dd, nullptr, out, 0);
        bn_partial<<<256, 256, 0, stream>>>(out, psum, psq);
        bn_stats<<<4, 256, 0, stream>>>(psum, psq, bns + (size_t)l * Dd,
                                        bnb + (size_t)l * Dd, abuf, cbuf);
        residual_gelu<<<1024, 256, 0, stream>>>(
            out, S0, (l < NL - 1) ? S0 : out, abuf, cbuf);
    }
}